// Round 16
// baseline (67.592 us; speedup 1.0000x reference)
//
#include <hip/hip_runtime.h>
#include <hip/hip_bf16.h>
#include <math.h>

#define BB 16
#define DD 128
#define NN 4096
#define KK 1024
// Positivity shift folded into e2': m = e2 + CADD - 2<z,e> = d^2 + (CADD - z^2).
// z^2 ~ chi2(128): max over 65k cols ~ 205 << 320 -> m > 0 always. Key quant
// at m<=~740 is <=0.125; TAU covers flip-window + quantization.
#define CADD 320.0f
#define TAU 0.45f

typedef __attribute__((ext_vector_type(8))) short short8;
typedef __attribute__((ext_vector_type(4))) float f32x4;

static __device__ __forceinline__ unsigned short f32_bf16_rne(float f) {
    unsigned u = __float_as_uint(f);
    u += 0x7FFF + ((u >> 16) & 1);
    return (unsigned short)(u >> 16);
}
static __device__ __forceinline__ unsigned umin32(unsigned a, unsigned b) { return a < b ? a : b; }
static __device__ __forceinline__ unsigned umax32(unsigned a, unsigned b) { return a > b ? a : b; }
static __device__ __forceinline__ unsigned umed3(unsigned a, unsigned b, unsigned c) {
    unsigned d;
    asm("v_med3_u32 %0, %1, %2, %3" : "=v"(d) : "v"(a), "v"(b), "v"(c));
    return d;
}

// ---------------------------------------------------------------------------
// e2'[k] = ||emb[k]||^2 + CADD  (f32)
// ---------------------------------------------------------------------------
__global__ void emb_sq_kernel(const float* __restrict__ emb,
                              float* __restrict__ e2) {
    int k = blockIdx.x * 256 + threadIdx.x;
    if (k >= KK) return;
    const float4* row = reinterpret_cast<const float4*>(emb + (size_t)k * DD);
    float a0 = 0.f, a1 = 0.f, a2 = 0.f, a3 = 0.f;
#pragma unroll
    for (int i = 0; i < DD / 16; ++i) {
        float4 v0 = row[i * 4 + 0];
        float4 v1 = row[i * 4 + 1];
        float4 v2 = row[i * 4 + 2];
        float4 v3 = row[i * 4 + 3];
        a0 += v0.x * v0.x + v0.y * v0.y + v0.z * v0.z + v0.w * v0.w;
        a1 += v1.x * v1.x + v1.y * v1.y + v1.z * v1.z + v1.w * v1.w;
        a2 += v2.x * v2.x + v2.y * v2.y + v2.z * v2.z + v2.w * v2.w;
        a3 += v3.x * v3.x + v3.y * v3.y + v3.z * v3.z + v3.w * v3.w;
    }
    e2[k] = (a0 + a1) + (a2 + a3) + CADD;
}

// ---------------------------------------------------------------------------
// Pack (-2 * emb) as SINGLE bf16 in MFMA A-fragment order (256 KB).
// Fragment (t, s, lane): k = t*16 + (lane&15), d = s*32 + (lane>>4)*8 + j.
// ---------------------------------------------------------------------------
__global__ void emb_pack_kernel(const float* __restrict__ emb,
                                short* __restrict__ epk) {
    int g = blockIdx.x * 256 + threadIdx.x;     // 16384 fragment-slots
    int lane = g & 63;
    int s    = (g >> 6) & 3;
    int t    = g >> 8;
    int k = t * 16 + (lane & 15);
    int d = s * 32 + ((lane >> 4) & 3) * 8;
    const float* src = emb + (size_t)k * DD + d;
    short8 h;
#pragma unroll
    for (int j = 0; j < 8; ++j) h[j] = (short)f32_bf16_rne(-2.0f * src[j]);
    *reinterpret_cast<short8*>(epk + (size_t)g * 8) = h;
}

// CE on packed u32 keys: a <- min, b <- max (2 VALU, no vcc)
#define CEU(a, b) { unsigned lo_ = umin32(a, b), hi_ = umax32(a, b); (a) = lo_; (b) = hi_; }
// merge two ascending-4 key lists; lowest 4 end sorted in A1..A4
#define MRG9(A1, A2, A3, A4, B1, B2, B3, B4) \
    CEU(A1, B1) CEU(A2, B2) CEU(A3, B3) CEU(A4, B4) \
    CEU(A3, B1) CEU(A4, B2) \
    CEU(A2, A3) \
    CEU(A4, B1) \
    CEU(A3, A4)

// ---------------------------------------------------------------------------
// Round-16 (defensive restructure): workgroup = ONE WAVE (64 threads) owning
// 32 cols x ALL 64 k-tiles in global order; grid 2048 (~8 blocks/CU). All
// resident waves on a CU march the SAME epk tile sequence -> shared L1 lines
// (the r14/r15 hypothesis, now with zero novel semantics: no barriers by
// construction, no cross-wave LDS, manual 16B-aligned LDS layout). Refine
// candidates broadcast via shfl (no LDS); trigger mask via ballot + ctz walk.
// Main loop / keys / TAU / f64 refine carried verbatim from r12/r13
// (absmax 0 six times). __launch_bounds__(64,4) = the proven 128-reg budget.
// ---------------------------------------------------------------------------
__global__ __launch_bounds__(64, 4)
void vq_mfma(const float* __restrict__ ze, const float* __restrict__ emb,
             const short* __restrict__ epk, const float* __restrict__ e2,
             float* __restrict__ out) {
    // manual layout, every region 16B-aligned:
    // [0, 8320)      ew[32][65] f32
    // [8320, 12416)  e2l[1024] f32
    // [12416, 12544) winner[32] int
    __shared__ __align__(16) char lds_[12544];
    float (*ew)[65] = reinterpret_cast<float(*)[65]>(lds_);
    float* e2l      = reinterpret_cast<float*>(lds_ + 8320);
    int*   winner   = reinterpret_cast<int*>(lds_ + 12416);

    const int lane = threadIdx.x;                 // 0..63, one wave
    const int b    = blockIdx.x >> 7;             // 128 blocks per batch entry
    const int n0   = (blockIdx.x & 127) * 32;     // wave's 32-col base
    const float* zb = ze + (size_t)b * DD * NN;

    const int nq = lane & 15;
    const int dq = (lane >> 4) & 3;

    // ---- e2 -> LDS (same wave writes & reads: no barrier needed) ----
#pragma unroll
    for (int i = 0; i < 4; ++i) {
        float4 v = *reinterpret_cast<const float4*>(e2 + i * 256 + lane * 4);
        *reinterpret_cast<float4*>(e2l + i * 256 + lane * 4) = v;
    }

    // ---- zf built directly in registers ----
    short8 zf[2][4];
#pragma unroll
    for (int cg = 0; cg < 2; ++cg) {
        const int col = n0 + cg * 16 + nq;
#pragma unroll
        for (int s = 0; s < 4; ++s) {
            const float* zp = zb + (size_t)(s * 32 + dq * 8) * NN + col;
#pragma unroll
            for (int j = 0; j < 8; ++j)
                zf[cg][s][j] = (short)f32_bf16_rne(zp[(size_t)j * NN]);
        }
    }

    // per-cg top-2 packed keys (ascending)
    unsigned K1[2], K2[2];
    K1[0] = K1[1] = K2[0] = K2[1] = 0xFFFFFFFFu;

    const short* ep = epk + (size_t)lane * 8;     // frag (t,s) at +(t*4+s)*512
    unsigned kb = (unsigned)(dq * 4);

    // ping-pong prologue: tiles 0 and 1
    short8 Af[2][4];
#pragma unroll
    for (int s = 0; s < 4; ++s) {
        Af[0][s] = *reinterpret_cast<const short8*>(ep + s * 512);
        Af[1][s] = *reinterpret_cast<const short8*>(ep + 2048 + s * 512);
    }
    float4 evC = *reinterpret_cast<const float4*>(e2l + dq * 4);

#pragma unroll 2
    for (int tt = 0; tt < 64; ++tt) {
        const int cur = tt & 1;                    // static under unroll 2
        // loop-top invariant: tiles tt, tt+1 in flight (8 loads) -> wait 4
        if (tt < 63) {
            asm volatile("s_waitcnt vmcnt(4)" ::: "memory");   // tile tt landed
        } else {
            asm volatile("s_waitcnt vmcnt(0)" ::: "memory");
        }
        __builtin_amdgcn_sched_barrier(0);

        // e2 for next tile from LDS (broadcast read, hidden under MFMA)
        const float4 evN = (tt < 63)
            ? *reinterpret_cast<const float4*>(e2l + (tt + 1) * 16 + dq * 4)
            : evC;

        f32x4 acc0 = {evC.x, evC.y, evC.z, evC.w};
        f32x4 acc1 = acc0;
#define STEP(AF, S) \
        acc0 = __builtin_amdgcn_mfma_f32_16x16x32_bf16(AF, zf[0][S], acc0, 0, 0, 0); \
        acc1 = __builtin_amdgcn_mfma_f32_16x16x32_bf16(AF, zf[1][S], acc1, 0, 0, 0);
        STEP(Af[cur][0], 0) STEP(Af[cur][1], 1) STEP(Af[cur][2], 2) STEP(Af[cur][3], 3)
#undef STEP

        // issue tile tt+2 into the buffer just consumed (clamped tail)
        {
            const int tn = (tt < 62) ? (tt + 2) : 63;
            const short* epn = ep + (size_t)tn * 2048;
#pragma unroll
            for (int s = 0; s < 4; ++s)
                Af[cur][s] = *reinterpret_cast<const short8*>(epn + s * 512);
        }

#pragma unroll
        for (int cg = 0; cg < 2; ++cg) {
            const f32x4 a = (cg == 0) ? acc0 : acc1;       // cg is unroll-const
#pragma unroll
            for (int r = 0; r < 4; ++r) {
                const unsigned x = (__float_as_uint(a[r]) & 0xFFFFFC00u) | (kb + r);
                K2[cg] = umed3(K1[cg], K2[cg], x);         // new 2nd-best
                K1[cg] = umin32(K1[cg], x);                // new best
            }
        }
        kb += 16;
        evC = evN;
    }

    // ---- dq merge: 4 sorted-2 lists -> sorted top-4 of the 8 candidates ----
    unsigned T1[2], T2[2], T3[2], T4[2];
#pragma unroll
    for (int cg = 0; cg < 2; ++cg) {
        unsigned A1 = K1[cg], A2 = K2[cg];
        unsigned B1 = __shfl_xor(A1, 16);
        unsigned B2 = __shfl_xor(A2, 16);
        CEU(A1, B1) CEU(A2, B2) CEU(A2, B1)      // sorted4: A1,A2,B1,B2
        unsigned C1 = __shfl_xor(A1, 32);
        unsigned C2 = __shfl_xor(A2, 32);
        unsigned C3 = __shfl_xor(B1, 32);
        unsigned C4 = __shfl_xor(B2, 32);
        MRG9(A1, A2, B1, B2, C1, C2, C3, C4)
        T1[cg] = A1; T2[cg] = A2; T3[cg] = B1; T4[cg] = B2;
    }

    // ---- finalize: lane c (<32) owns column n0 + c; lanes >=32 duplicate ----
    const int cgid = (lane >> 4) & 1;
    const unsigned S1 = cgid ? T1[1] : T1[0];
    const unsigned S2 = cgid ? T2[1] : T2[0];
    const unsigned S3 = cgid ? T3[1] : T3[0];
    const unsigned S4 = cgid ? T4[1] : T4[0];
    {
        const int c = lane & 31;
        if (lane < 32) winner[c] = (int)(S1 & 0x3FFu);
        const float M1 = __uint_as_float(S1 & 0xFFFFFC00u);
        const float M2 = __uint_as_float(S2 & 0xFFFFFC00u);
        const bool trig = (lane < 32) && ((M2 - M1) < TAU);
        unsigned m32 = (unsigned)(__ballot(trig) & 0xFFFFFFFFull);

        // ---- wave-cooperative exact f64 refine (~15% of columns) ----
        while (m32) {
            const int c2 = __builtin_ctz(m32);
            m32 &= m32 - 1;
            // broadcast column c2's candidates from lane c2 (registers)
            const int I0 = (int)((unsigned)__shfl((int)S1, c2) & 0x3FFu);
            const int I1 = (int)((unsigned)__shfl((int)S2, c2) & 0x3FFu);
            const int I2 = (int)((unsigned)__shfl((int)S3, c2) & 0x3FFu);
            const int I3 = (int)((unsigned)__shfl((int)S4, c2) & 0x3FFu);
            const int coln = n0 + c2;
            double s0 = 0.0, s1 = 0.0, s2 = 0.0, s3 = 0.0;
#pragma unroll
            for (int h = 0; h < 2; ++h) {
                const int d = h * 64 + lane;
                const double zv = (double)zb[(size_t)d * NN + coln];
                double q;
                q = zv - (double)emb[(size_t)I0 * DD + d]; s0 += q * q;
                q = zv - (double)emb[(size_t)I1 * DD + d]; s1 += q * q;
                q = zv - (double)emb[(size_t)I2 * DD + d]; s2 += q * q;
                q = zv - (double)emb[(size_t)I3 * DD + d]; s3 += q * q;
            }
#pragma unroll
            for (int off = 1; off < 64; off <<= 1) {
                s0 += __shfl_xor(s0, off);
                s1 += __shfl_xor(s1, off);
                s2 += __shfl_xor(s2, off);
                s3 += __shfl_xor(s3, off);
            }
            int best = I0; double db = s0;
            if (s1 < db || (s1 == db && I1 < best)) { db = s1; best = I1; }
            if (s2 < db || (s2 == db && I2 < best)) { db = s2; best = I2; }
            if (s3 < db || (s3 == db && I3 < best)) { db = s3; best = I3; }
            if (lane == 0) winner[c2] = best;
        }
    }

    // ---- epilogue: two d-half passes through ew[32][65] ----
#pragma unroll 1
    for (int pass = 0; pass < 2; ++pass) {
        const int dbase = pass * 64;
        // stage: row rr's d-half (lane = d offset); wave-uniform winner read
#pragma unroll 4
        for (int rr = 0; rr < 32; ++rr) {
            const int idx = winner[rr];
            ew[rr][lane] = emb[(size_t)idx * DD + dbase + lane];
        }
        // write: col = lane&31, 2 d per iter (stride 65 -> conflict-free)
        {
            const int c = lane & 31;
            const int half = lane >> 5;
            const int coln = n0 + c;
#pragma unroll 4
            for (int dd = 0; dd < 32; ++dd) {
                const int dl = dd * 2 + half;         // 0..63 within half
                const int d  = dbase + dl;
                const float zv  = zb[(size_t)d * NN + coln];
                const float evv = ew[c][dl];
                out[((size_t)b * DD + d) * NN + coln] = zv + (evv - zv);
            }
        }
    }
}

// ---------------------------------------------------------------------------
extern "C" void kernel_launch(void* const* d_in, const int* in_sizes, int n_in,
                              void* d_out, int out_size, void* d_ws, size_t ws_size,
                              hipStream_t stream) {
    (void)in_sizes; (void)n_in; (void)out_size; (void)ws_size;
    const float* ze  = (const float*)d_in[0];   // (B, D, N) f32
    const float* emb = (const float*)d_in[1];   // (K, D)    f32
    float*       out = (float*)d_out;           // (B, D, N) f32

    char* ws = (char*)d_ws;
    short* epk = (short*)ws;                          // 256 KB packed -2*emb
    float* e2  = (float*)(ws + (size_t)KK * DD * 2);  // 4 KB (+CADD folded)

    emb_sq_kernel<<<KK / 256, 256, 0, stream>>>(emb, e2);
    emb_pack_kernel<<<(KK * DD / 8) / 256, 256, 0, stream>>>(emb, epk);
    vq_mfma<<<(BB * NN) / 32, 64, 0, stream>>>(ze, emb, epk, e2, out);
}

// Round 17
// 55.326 us; speedup vs baseline: 1.2217x; 1.2217x over previous
//
#include <hip/hip_runtime.h>
#include <hip/hip_bf16.h>
#include <math.h>

#define BB 16
#define DD 128
#define NN 4096
#define KK 1024
// Positivity shift folded into e2': m = e2 + CADD - 2<z,e> = d^2 + (CADD - z^2).
// z^2 ~ chi2(128): max over 65k cols ~ 205 << 320 -> m > 0 always. Key quant
// at m<=~740 is <=0.125; TAU covers flip-window + quantization.
#define CADD 320.0f
#define TAU 0.45f

typedef __attribute__((ext_vector_type(8))) short short8;
typedef __attribute__((ext_vector_type(4))) float f32x4;

typedef __attribute__((address_space(3))) char       lds_char;
typedef __attribute__((address_space(1))) const char gbl_char;

static __device__ __forceinline__ unsigned short f32_bf16_rne(float f) {
    unsigned u = __float_as_uint(f);
    u += 0x7FFF + ((u >> 16) & 1);
    return (unsigned short)(u >> 16);
}
static __device__ __forceinline__ unsigned umin32(unsigned a, unsigned b) { return a < b ? a : b; }
static __device__ __forceinline__ unsigned umax32(unsigned a, unsigned b) { return a > b ? a : b; }
static __device__ __forceinline__ unsigned umed3(unsigned a, unsigned b, unsigned c) {
    unsigned d;
    asm("v_med3_u32 %0, %1, %2, %3" : "=v"(d) : "v"(a), "v"(b), "v"(c));
    return d;
}

// ---------------------------------------------------------------------------
// e2'[k] = ||emb[k]||^2 + CADD  (f32)
// ---------------------------------------------------------------------------
__global__ void emb_sq_kernel(const float* __restrict__ emb,
                              float* __restrict__ e2) {
    int k = blockIdx.x * 256 + threadIdx.x;
    if (k >= KK) return;
    const float4* row = reinterpret_cast<const float4*>(emb + (size_t)k * DD);
    float a0 = 0.f, a1 = 0.f, a2 = 0.f, a3 = 0.f;
#pragma unroll
    for (int i = 0; i < DD / 16; ++i) {
        float4 v0 = row[i * 4 + 0];
        float4 v1 = row[i * 4 + 1];
        float4 v2 = row[i * 4 + 2];
        float4 v3 = row[i * 4 + 3];
        a0 += v0.x * v0.x + v0.y * v0.y + v0.z * v0.z + v0.w * v0.w;
        a1 += v1.x * v1.x + v1.y * v1.y + v1.z * v1.z + v1.w * v1.w;
        a2 += v2.x * v2.x + v2.y * v2.y + v2.z * v2.z + v2.w * v2.w;
        a3 += v3.x * v3.x + v3.y * v3.y + v3.z * v3.z + v3.w * v3.w;
    }
    e2[k] = (a0 + a1) + (a2 + a3) + CADD;
}

// ---------------------------------------------------------------------------
// Pack (-2 * emb) as SINGLE bf16 in MFMA A-fragment order (256 KB).
// Fragment (t, s, lane): k = t*16 + (lane&15), d = s*32 + (lane>>4)*8 + j.
// ---------------------------------------------------------------------------
__global__ void emb_pack_kernel(const float* __restrict__ emb,
                                short* __restrict__ epk) {
    int g = blockIdx.x * 256 + threadIdx.x;     // 16384 fragment-slots
    int lane = g & 63;
    int s    = (g >> 6) & 3;
    int t    = g >> 8;
    int k = t * 16 + (lane & 15);
    int d = s * 32 + ((lane >> 4) & 3) * 8;
    const float* src = emb + (size_t)k * DD + d;
    short8 h;
#pragma unroll
    for (int j = 0; j < 8; ++j) h[j] = (short)f32_bf16_rne(-2.0f * src[j]);
    *reinterpret_cast<short8*>(epk + (size_t)g * 8) = h;
}

// CE on packed u32 keys: a <- min, b <- max (2 VALU, no vcc)
#define CEU(a, b) { unsigned lo_ = umin32(a, b), hi_ = umax32(a, b); (a) = lo_; (b) = hi_; }
// merge two ascending-4 key lists; lowest 4 end sorted in A1..A4
#define MRG9(A1, A2, A3, A4, B1, B2, B3, B4) \
    CEU(A1, B1) CEU(A2, B2) CEU(A3, B3) CEU(A4, B4) \
    CEU(A3, B1) CEU(A4, B2) \
    CEU(A2, A3) \
    CEU(A4, B1) \
    CEU(A3, A4)

// ---------------------------------------------------------------------------
// Round-17: r12 structure (block = 32 cols, 4 waves split K quarters; best
// measured) + the ONE mechanism the compiler cannot undo: epk staged through
// wave-private LDS double-buffers via global_load_lds (r16 showed VGPR=60 --
// the compiler has been rematerializing every register-prefetch attempt,
// leaving ~900 cyc/tile of exposed latency). 4 gl_lds(16B)/tile, counted
// vmcnt(4), ds_read_b128 consume. Live regs ~75 -> no spills at (256,4).
// Key/trigger/refine/epilogue semantics as r12 (absmax 0 x6).
// ---------------------------------------------------------------------------
__global__ __launch_bounds__(256, 4)
void vq_mfma(const float* __restrict__ ze, const float* __restrict__ emb,
             const short* __restrict__ epk, const float* __restrict__ e2,
             float* __restrict__ out) {
    // stg: 4 waves x 2 bufs x 4KB = 32 KB; unioned as ew[32][129] after loop
    __shared__ __align__(16) char stg[32768];
    __shared__ float e2l[KK];                     // 4 KB (wave-private quarters)
    __shared__ unsigned kbuf[4][32][4];           // 2 KB
    __shared__ int winner_s[32];
    __shared__ int rlist[32];
    __shared__ int rcnt;

    const int tid  = threadIdx.x;
    const int lane = tid & 63;
    const int wave = tid >> 6;
    const int b    = blockIdx.x >> 7;             // 128 blocks per batch entry
    const int n0b  = (blockIdx.x & 127) * 32;     // block's 32-col base
    const float* zb = ze + (size_t)b * DD * NN;

    const int nq = lane & 15;
    const int dq = (lane >> 4) & 3;

    // ---- e2 quarter -> wave-private LDS ----
    float* e2w = e2l + wave * 256;
#pragma unroll
    for (int i = 0; i < 4; ++i)
        e2w[i * 64 + lane] = e2[wave * 256 + i * 64 + lane];

    // ---- zf built directly in registers (wave-shared cols) ----
    short8 zf[2][4];
#pragma unroll
    for (int cg = 0; cg < 2; ++cg) {
        const int col = n0b + cg * 16 + nq;
#pragma unroll
        for (int s = 0; s < 4; ++s) {
            const float* zp = zb + (size_t)(s * 32 + dq * 8) * NN + col;
#pragma unroll
            for (int j = 0; j < 8; ++j)
                zf[cg][s][j] = (short)f32_bf16_rne(zp[(size_t)j * NN]);
        }
    }

    // per-cg top-2 packed keys (ascending)
    unsigned K1[2], K2[2];
    K1[0] = K1[1] = K2[0] = K2[1] = 0xFFFFFFFFu;

    const int t0 = wave * 16;                     // this wave's 16 k-tiles
    const short* ep_l = epk + (size_t)(t0 * 4) * 512 + (size_t)lane * 8;
    char* stw = stg + wave * 8192;                // wave-private staging

    // issue one k-tile's 4 s-frags into buf (tt&1) — un-sinkable prefetch
    auto issue_tile = [&](int tt) {
        char* lb = stw + (tt & 1) * 4096;
        const short* gs = ep_l + (size_t)tt * 2048;   // +4 frags * 512 shorts
#pragma unroll
        for (int s = 0; s < 4; ++s) {
            __builtin_amdgcn_global_load_lds(
                (gbl_char*)(gs + s * 512),
                (lds_char*)(lb + s * 1024), 16, 0, 0);
        }
    };

    // drain prologue vmem so loop vmcnt counts only gl_lds (4 per tile)
    asm volatile("s_waitcnt vmcnt(0)" ::: "memory");
    issue_tile(0);

    unsigned kb = (unsigned)(t0 * 16 + dq * 4);
    const int lro = lane * 16;

#pragma unroll 2
    for (int tt = 0; tt < 16; ++tt) {
        if (tt < 15) {
            issue_tile(tt + 1);
            asm volatile("s_waitcnt vmcnt(4)" ::: "memory");  // tile tt landed
        } else {
            asm volatile("s_waitcnt vmcnt(0)" ::: "memory");
        }
        __builtin_amdgcn_sched_barrier(0);

        const char* lb = stw + (tt & 1) * 4096;
        const float4 ev = *reinterpret_cast<const float4*>(e2w + tt * 16 + dq * 4);
        f32x4 acc0 = {ev.x, ev.y, ev.z, ev.w};
        f32x4 acc1 = acc0;
#pragma unroll
        for (int s = 0; s < 4; ++s) {
            const short8 af = *reinterpret_cast<const short8*>(lb + s * 1024 + lro);
            acc0 = __builtin_amdgcn_mfma_f32_16x16x32_bf16(af, zf[0][s], acc0, 0, 0, 0);
            acc1 = __builtin_amdgcn_mfma_f32_16x16x32_bf16(af, zf[1][s], acc1, 0, 0, 0);
        }

#pragma unroll
        for (int cg = 0; cg < 2; ++cg) {
            const f32x4 a = (cg == 0) ? acc0 : acc1;       // cg is unroll-const
#pragma unroll
            for (int r = 0; r < 4; ++r) {
                const unsigned x = (__float_as_uint(a[r]) & 0xFFFFFC00u) | (kb + r);
                K2[cg] = umed3(K1[cg], K2[cg], x);         // new 2nd-best
                K1[cg] = umin32(K1[cg], x);                // new best
            }
        }
        kb += 16;
    }

    // ---- dq merge: 4 sorted-2 lists -> sorted top-4 of the 8 candidates ----
    unsigned T1[2], T2[2], T3[2], T4[2];
#pragma unroll
    for (int cg = 0; cg < 2; ++cg) {
        unsigned A1 = K1[cg], A2 = K2[cg];
        unsigned B1 = __shfl_xor(A1, 16);
        unsigned B2 = __shfl_xor(A2, 16);
        CEU(A1, B1) CEU(A2, B2) CEU(A2, B1)      // sorted4: A1,A2,B1,B2
        unsigned C1 = __shfl_xor(A1, 32);
        unsigned C2 = __shfl_xor(A2, 32);
        unsigned C3 = __shfl_xor(B1, 32);
        unsigned C4 = __shfl_xor(B2, 32);
        MRG9(A1, A2, B1, B2, C1, C2, C3, C4)
        T1[cg] = A1; T2[cg] = A2; T3[cg] = B1; T4[cg] = B2;
    }

    // lane c (0..31): column n0b + c has its list in cg = c>>4
    if (lane < 32) {
        const int cgid = lane >> 4;
        kbuf[wave][lane][0] = cgid ? T1[1] : T1[0];
        kbuf[wave][lane][1] = cgid ? T2[1] : T2[0];
        kbuf[wave][lane][2] = cgid ? T3[1] : T3[0];
        kbuf[wave][lane][3] = cgid ? T4[1] : T4[0];
    }
    __syncthreads();

    // ---- wave 0: merge the 4 k-quarters per column, build refine list ----
    if (wave == 0) {
        const int c = lane & 31;
        unsigned A1 = kbuf[0][c][0], A2 = kbuf[0][c][1];
        unsigned A3 = kbuf[0][c][2], A4 = kbuf[0][c][3];
#pragma unroll
        for (int q = 1; q < 4; ++q) {
            unsigned B1 = kbuf[q][c][0], B2 = kbuf[q][c][1];
            unsigned B3 = kbuf[q][c][2], B4 = kbuf[q][c][3];
            MRG9(A1, A2, A3, A4, B1, B2, B3, B4)
        }
        const float M1 = __uint_as_float(A1 & 0xFFFFFC00u);
        const float M2 = __uint_as_float(A2 & 0xFFFFFC00u);
        const bool trig = (lane < 32) && ((M2 - M1) < TAU);
        if (lane < 32) {
            winner_s[c] = (int)(A1 & 0x3FFu);
            kbuf[0][c][0] = A1; kbuf[0][c][1] = A2;       // refine candidates
            kbuf[0][c][2] = A3; kbuf[0][c][3] = A4;
        }
        const unsigned long long mask = __ballot(trig);
        if (trig) {
            const int idx = __popcll(mask & ((1ull << lane) - 1ull));
            rlist[idx] = c;
        }
        if (lane == 0) rcnt = (int)__popcll(mask);
    }
    __syncthreads();

    // ---- cooperative exact f64 refine (~15% of columns) ----
    {
        const int rc = rcnt;
        for (int j = wave; j < rc; j += 4) {
            const int c = rlist[j];
            const int coln = n0b + c;
            const int I0 = (int)(kbuf[0][c][0] & 0x3FFu);
            const int I1 = (int)(kbuf[0][c][1] & 0x3FFu);
            const int I2 = (int)(kbuf[0][c][2] & 0x3FFu);
            const int I3 = (int)(kbuf[0][c][3] & 0x3FFu);
            double s0 = 0.0, s1 = 0.0, s2 = 0.0, s3 = 0.0;
#pragma unroll
            for (int h = 0; h < 2; ++h) {
                const int d = h * 64 + lane;
                const double zv = (double)zb[(size_t)d * NN + coln];
                double q;
                q = zv - (double)emb[(size_t)I0 * DD + d]; s0 += q * q;
                q = zv - (double)emb[(size_t)I1 * DD + d]; s1 += q * q;
                q = zv - (double)emb[(size_t)I2 * DD + d]; s2 += q * q;
                q = zv - (double)emb[(size_t)I3 * DD + d]; s3 += q * q;
            }
#pragma unroll
            for (int off = 1; off < 64; off <<= 1) {
                s0 += __shfl_xor(s0, off);
                s1 += __shfl_xor(s1, off);
                s2 += __shfl_xor(s2, off);
                s3 += __shfl_xor(s3, off);
            }
            int best = I0; double db = s0;
            if (s1 < db || (s1 == db && I1 < best)) { db = s1; best = I1; }
            if (s2 < db || (s2 == db && I2 < best)) { db = s2; best = I2; }
            if (s3 < db || (s3 == db && I3 < best)) { db = s3; best = I3; }
            if (lane == 0) winner_s[c] = best;
        }
    }
    __syncthreads();

    // ---- epilogue: stage 32 winner rows in LDS (stg union), coalesced out
    float (*ew)[DD + 1] = reinterpret_cast<float(*)[DD + 1]>(stg);
#pragma unroll 2
    for (int rr = 0; rr < 8; ++rr) {
        const int r = wave * 8 + rr;
        const int idx = winner_s[r];                  // wave-uniform per iter
        ew[r][lane]      = emb[(size_t)idx * DD + lane];
        ew[r][lane + 64] = emb[(size_t)idx * DD + lane + 64];
    }
    __syncthreads();

    // lane -> (col = lane&31, d-offset = lane>>5); 16 iters cover 32 d/wave
    {
        const int c = lane & 31;
        const int coln = n0b + c;
#pragma unroll 4
        for (int dd = 0; dd < 16; ++dd) {
            const int d = wave * 32 + dd * 2 + (lane >> 5);
            const float zv = zb[(size_t)d * NN + coln];
            const float evv = ew[c][d];
            out[((size_t)b * DD + d) * NN + coln] = zv + (evv - zv);
        }
    }
}

// ---------------------------------------------------------------------------
extern "C" void kernel_launch(void* const* d_in, const int* in_sizes, int n_in,
                              void* d_out, int out_size, void* d_ws, size_t ws_size,
                              hipStream_t stream) {
    (void)in_sizes; (void)n_in; (void)out_size; (void)ws_size;
    const float* ze  = (const float*)d_in[0];   // (B, D, N) f32
    const float* emb = (const float*)d_in[1];   // (K, D)    f32
    float*       out = (float*)d_out;           // (B, D, N) f32

    char* ws = (char*)d_ws;
    short* epk = (short*)ws;                          // 256 KB packed -2*emb
    float* e2  = (float*)(ws + (size_t)KK * DD * 2);  // 4 KB (+CADD folded)

    emb_sq_kernel<<<KK / 256, 256, 0, stream>>>(emb, e2);
    emb_pack_kernel<<<(KK * DD / 8) / 256, 256, 0, stream>>>(emb, epk);
    vq_mfma<<<(BB * NN) / 32, 256, 0, stream>>>(ze, emb, epk, e2, out);
}

// Round 18
// 49.058 us; speedup vs baseline: 1.3778x; 1.1278x over previous
//
#include <hip/hip_runtime.h>
#include <hip/hip_bf16.h>
#include <math.h>

#define BB 16
#define DD 128
#define NN 4096
#define KK 1024
// Positivity shift folded into e2': m = e2 + CADD - 2<z,e> = d^2 + (CADD - z^2).
// z^2 ~ chi2(128): max over 65k cols ~ 205 << 320 -> m > 0 always. Key quant
// at m<=~740 is <=0.125; TAU covers flip-window + quantization.
#define CADD 320.0f
#define TAU 0.45f

typedef __attribute__((ext_vector_type(8))) short short8;
typedef __attribute__((ext_vector_type(4))) float f32x4;

static __device__ __forceinline__ unsigned short f32_bf16_rne(float f) {
    unsigned u = __float_as_uint(f);
    u += 0x7FFF + ((u >> 16) & 1);
    return (unsigned short)(u >> 16);
}
static __device__ __forceinline__ unsigned umin32(unsigned a, unsigned b) { return a < b ? a : b; }
static __device__ __forceinline__ unsigned umax32(unsigned a, unsigned b) { return a > b ? a : b; }
static __device__ __forceinline__ unsigned umed3(unsigned a, unsigned b, unsigned c) {
    unsigned d;
    asm("v_med3_u32 %0, %1, %2, %3" : "=v"(d) : "v"(a), "v"(b), "v"(c));
    return d;
}

// ---------------------------------------------------------------------------
// e2'[k] = ||emb[k]||^2 + CADD  (f32)
// ---------------------------------------------------------------------------
__global__ void emb_sq_kernel(const float* __restrict__ emb,
                              float* __restrict__ e2) {
    int k = blockIdx.x * 256 + threadIdx.x;
    if (k >= KK) return;
    const float4* row = reinterpret_cast<const float4*>(emb + (size_t)k * DD);
    float a0 = 0.f, a1 = 0.f, a2 = 0.f, a3 = 0.f;
#pragma unroll
    for (int i = 0; i < DD / 16; ++i) {
        float4 v0 = row[i * 4 + 0];
        float4 v1 = row[i * 4 + 1];
        float4 v2 = row[i * 4 + 2];
        float4 v3 = row[i * 4 + 3];
        a0 += v0.x * v0.x + v0.y * v0.y + v0.z * v0.z + v0.w * v0.w;
        a1 += v1.x * v1.x + v1.y * v1.y + v1.z * v1.z + v1.w * v1.w;
        a2 += v2.x * v2.x + v2.y * v2.y + v2.z * v2.z + v2.w * v2.w;
        a3 += v3.x * v3.x + v3.y * v3.y + v3.z * v3.z + v3.w * v3.w;
    }
    e2[k] = (a0 + a1) + (a2 + a3) + CADD;
}

// ---------------------------------------------------------------------------
// Pack (-2 * emb) as SINGLE bf16 in MFMA A-fragment order (256 KB).
// Fragment (t, s, lane): k = t*16 + (lane&15), d = s*32 + (lane>>4)*8 + j.
// ---------------------------------------------------------------------------
__global__ void emb_pack_kernel(const float* __restrict__ emb,
                                short* __restrict__ epk) {
    int g = blockIdx.x * 256 + threadIdx.x;     // 16384 fragment-slots
    int lane = g & 63;
    int s    = (g >> 6) & 3;
    int t    = g >> 8;
    int k = t * 16 + (lane & 15);
    int d = s * 32 + ((lane >> 4) & 3) * 8;
    const float* src = emb + (size_t)k * DD + d;
    short8 h;
#pragma unroll
    for (int j = 0; j < 8; ++j) h[j] = (short)f32_bf16_rne(-2.0f * src[j]);
    *reinterpret_cast<short8*>(epk + (size_t)g * 8) = h;
}

// CE on packed u32 keys: a <- min, b <- max (2 VALU, no vcc)
#define CEU(a, b) { unsigned lo_ = umin32(a, b), hi_ = umax32(a, b); (a) = lo_; (b) = hi_; }
// merge two ascending-4 key lists; lowest 4 end sorted in A1..A4
#define MRG9(A1, A2, A3, A4, B1, B2, B3, B4) \
    CEU(A1, B1) CEU(A2, B2) CEU(A3, B3) CEU(A4, B4) \
    CEU(A3, B1) CEU(A4, B2) \
    CEU(A2, A3) \
    CEU(A4, B1) \
    CEU(A3, A4)

// ---------------------------------------------------------------------------
// Round-18 (un-pinning round): byte-identical semantics to r12 (absmax 0 x7)
// with ALL manual scheduling removed from the main loop. Every flat round
// (r10-r17, 44-57 us) shared per-tile `s_waitcnt` asm + sched_barrier(0);
// the guide's m141 measured sched_barrier(0) pinning at -40%, and VGPR=52-60
// proves the compiler was sinking my prefetch loads anyway -- so the vmcnt
// waits were serializing each tile against loads issued in the SAME
// iteration. Let the compiler software-pipeline (it inserts fine-grained
// counted waits on its own, per m97 asm). unroll 4 for a cross-tile window.
// ---------------------------------------------------------------------------
__global__ __launch_bounds__(256, 4)
void vq_mfma(const float* __restrict__ ze, const float* __restrict__ emb,
             const short* __restrict__ epk, const float* __restrict__ e2,
             float* __restrict__ out) {
    // union: z-stage frags (8 KB) -> ew[32][129] (16.5 KB) after main loop
    __shared__ __align__(16) char ubuf[(DD + 1) * 32 * 4];   // 16512 B
    __shared__ unsigned kbuf[4][32][4];
    __shared__ int winner_s[32];
    __shared__ int rlist[32];
    __shared__ int rcnt;

    short* zstage = reinterpret_cast<short*>(ubuf);          // 4096 shorts

    const int tid  = threadIdx.x;
    const int lane = tid & 63;
    const int wave = tid >> 6;
    const int b    = blockIdx.x >> 7;             // 128 blocks per batch entry
    const int n0b  = (blockIdx.x & 127) * 32;     // block's 32-col base
    const float* zb = ze + (size_t)b * DD * NN;

    const int nq = lane & 15;
    const int dq = (lane >> 4) & 3;

    // ---- cooperative z staging: thread = frag slot (cg 0 and 1) ----
#pragma unroll
    for (int cg = 0; cg < 2; ++cg) {
        const int col = n0b + cg * 16 + nq;
        const int d0  = wave * 32 + dq * 8;
        const float* zp = zb + (size_t)d0 * NN + col;
        short8 h;
#pragma unroll
        for (int j = 0; j < 8; ++j) h[j] = (short)f32_bf16_rne(zp[(size_t)j * NN]);
        *reinterpret_cast<short8*>(zstage + (cg * 256 + wave * 64 + lane) * 8) = h;
    }
    __syncthreads();

    // ---- read zf frags from LDS (ds_read_b128, conflict-free) ----
    short8 zf[2][4];
#pragma unroll
    for (int cg = 0; cg < 2; ++cg)
#pragma unroll
        for (int s = 0; s < 4; ++s)
            zf[cg][s] = *reinterpret_cast<const short8*>(
                zstage + ((cg * 4 + s) * 64 + lane) * 8);
    __syncthreads();               // zstage dead; ubuf reusable as ew later

    // per-cg top-2 packed keys (ascending)
    unsigned K1[2], K2[2];
    K1[0] = K1[1] = K2[0] = K2[1] = 0xFFFFFFFFu;

    const int t0 = wave * 16;                     // this wave's 16 k-tiles
    const short* ep  = epk + (size_t)(t0 * 4) * 512 + (size_t)lane * 8;
    const float* e2p = e2 + t0 * 16 + dq * 4;
    unsigned kb = (unsigned)(t0 * 16 + dq * 4);

    short8 aC0 = *reinterpret_cast<const short8*>(ep);
    short8 aC1 = *reinterpret_cast<const short8*>(ep + 512);
    short8 aC2 = *reinterpret_cast<const short8*>(ep + 1024);
    short8 aC3 = *reinterpret_cast<const short8*>(ep + 1536);
    float4 evC = *reinterpret_cast<const float4*>(e2p);

#pragma unroll 4
    for (int tt = 0; tt < 16; ++tt) {
        short8 aN0, aN1, aN2, aN3; float4 evN;
        if (tt < 15) {
            aN0 = *reinterpret_cast<const short8*>(ep + 2048);
            aN1 = *reinterpret_cast<const short8*>(ep + 2560);
            aN2 = *reinterpret_cast<const short8*>(ep + 3072);
            aN3 = *reinterpret_cast<const short8*>(ep + 3584);
            evN = *reinterpret_cast<const float4*>(e2p + 16);
        }
        // no manual waits / no sched_barrier: compiler schedules + waits

        // acc init = e2' copy (CADD pre-folded; no z2 terms)
        f32x4 acc0 = {evC.x, evC.y, evC.z, evC.w};
        f32x4 acc1 = acc0;
#define STEP(AF, S) \
        acc0 = __builtin_amdgcn_mfma_f32_16x16x32_bf16(AF, zf[0][S], acc0, 0, 0, 0); \
        acc1 = __builtin_amdgcn_mfma_f32_16x16x32_bf16(AF, zf[1][S], acc1, 0, 0, 0);
        STEP(aC0, 0) STEP(aC1, 1) STEP(aC2, 2) STEP(aC3, 3)
#undef STEP

#pragma unroll
        for (int cg = 0; cg < 2; ++cg) {
            const f32x4 a = (cg == 0) ? acc0 : acc1;       // cg is unroll-const
#pragma unroll
            for (int r = 0; r < 4; ++r) {
                const unsigned x = (__float_as_uint(a[r]) & 0xFFFFFC00u) | (kb + r);
                K2[cg] = umed3(K1[cg], K2[cg], x);         // new 2nd-best
                K1[cg] = umin32(K1[cg], x);                // new best
            }
        }
        kb += 16; ep += 2048; e2p += 16;
        aC0 = aN0; aC1 = aN1; aC2 = aN2; aC3 = aN3; evC = evN;
    }

    // ---- dq merge: 4 sorted-2 lists -> sorted top-4 of the 8 candidates ----
    unsigned T1[2], T2[2], T3[2], T4[2];
#pragma unroll
    for (int cg = 0; cg < 2; ++cg) {
        unsigned A1 = K1[cg], A2 = K2[cg];
        unsigned B1 = __shfl_xor(A1, 16);
        unsigned B2 = __shfl_xor(A2, 16);
        CEU(A1, B1) CEU(A2, B2) CEU(A2, B1)      // sorted4: A1,A2,B1,B2
        unsigned C1 = __shfl_xor(A1, 32);
        unsigned C2 = __shfl_xor(A2, 32);
        unsigned C3 = __shfl_xor(B1, 32);
        unsigned C4 = __shfl_xor(B2, 32);
        MRG9(A1, A2, B1, B2, C1, C2, C3, C4)
        T1[cg] = A1; T2[cg] = A2; T3[cg] = B1; T4[cg] = B2;
    }

    // lane c (0..31): column n0b + c has its list in cg = c>>4
    if (lane < 32) {
        const int cgid = lane >> 4;
        kbuf[wave][lane][0] = cgid ? T1[1] : T1[0];
        kbuf[wave][lane][1] = cgid ? T2[1] : T2[0];
        kbuf[wave][lane][2] = cgid ? T3[1] : T3[0];
        kbuf[wave][lane][3] = cgid ? T4[1] : T4[0];
    }
    __syncthreads();

    // ---- wave 0: merge the 4 k-quarters per column, build refine list ----
    if (wave == 0) {
        const int c = lane & 31;
        unsigned A1 = kbuf[0][c][0], A2 = kbuf[0][c][1];
        unsigned A3 = kbuf[0][c][2], A4 = kbuf[0][c][3];
#pragma unroll
        for (int q = 1; q < 4; ++q) {
            unsigned B1 = kbuf[q][c][0], B2 = kbuf[q][c][1];
            unsigned B3 = kbuf[q][c][2], B4 = kbuf[q][c][3];
            MRG9(A1, A2, A3, A4, B1, B2, B3, B4)
        }
        const float M1 = __uint_as_float(A1 & 0xFFFFFC00u);
        const float M2 = __uint_as_float(A2 & 0xFFFFFC00u);
        const bool trig = (lane < 32) && ((M2 - M1) < TAU);
        if (lane < 32) {
            winner_s[c] = (int)(A1 & 0x3FFu);
            kbuf[0][c][0] = A1; kbuf[0][c][1] = A2;       // refine candidates
            kbuf[0][c][2] = A3; kbuf[0][c][3] = A4;
        }
        const unsigned long long mask = __ballot(trig);
        if (trig) {
            const int idx = __popcll(mask & ((1ull << lane) - 1ull));
            rlist[idx] = c;
        }
        if (lane == 0) rcnt = (int)__popcll(mask);
    }
    __syncthreads();

    // ---- cooperative exact f64 refine (~15% of columns) ----
    {
        const int rc = rcnt;
        for (int j = wave; j < rc; j += 4) {
            const int c = rlist[j];
            const int coln = n0b + c;
            const int I0 = (int)(kbuf[0][c][0] & 0x3FFu);
            const int I1 = (int)(kbuf[0][c][1] & 0x3FFu);
            const int I2 = (int)(kbuf[0][c][2] & 0x3FFu);
            const int I3 = (int)(kbuf[0][c][3] & 0x3FFu);
            double s0 = 0.0, s1 = 0.0, s2 = 0.0, s3 = 0.0;
#pragma unroll
            for (int h = 0; h < 2; ++h) {
                const int d = h * 64 + lane;
                const double zv = (double)zb[(size_t)d * NN + coln];
                double q;
                q = zv - (double)emb[(size_t)I0 * DD + d]; s0 += q * q;
                q = zv - (double)emb[(size_t)I1 * DD + d]; s1 += q * q;
                q = zv - (double)emb[(size_t)I2 * DD + d]; s2 += q * q;
                q = zv - (double)emb[(size_t)I3 * DD + d]; s3 += q * q;
            }
#pragma unroll
            for (int off = 1; off < 64; off <<= 1) {
                s0 += __shfl_xor(s0, off);
                s1 += __shfl_xor(s1, off);
                s2 += __shfl_xor(s2, off);
                s3 += __shfl_xor(s3, off);
            }
            int best = I0; double db = s0;
            if (s1 < db || (s1 == db && I1 < best)) { db = s1; best = I1; }
            if (s2 < db || (s2 == db && I2 < best)) { db = s2; best = I2; }
            if (s3 < db || (s3 == db && I3 < best)) { db = s3; best = I3; }
            if (lane == 0) winner_s[c] = best;
        }
    }
    __syncthreads();

    // ---- epilogue: stage 32 winner rows in LDS (ubuf reuse), coalesced out
    float (*ew)[DD + 1] = reinterpret_cast<float(*)[DD + 1]>(ubuf);
#pragma unroll 2
    for (int rr = 0; rr < 8; ++rr) {
        const int r = wave * 8 + rr;
        const int idx = winner_s[r];                  // wave-uniform per iter
        ew[r][lane]      = emb[(size_t)idx * DD + lane];
        ew[r][lane + 64] = emb[(size_t)idx * DD + lane + 64];
    }
    __syncthreads();

    // lane -> (col = lane&31, d-offset = lane>>5); 16 iters cover 32 d/wave
    {
        const int c = lane & 31;
        const int coln = n0b + c;
#pragma unroll 4
        for (int dd = 0; dd < 16; ++dd) {
            const int d = wave * 32 + dd * 2 + (lane >> 5);
            const float zv = zb[(size_t)d * NN + coln];
            const float evv = ew[c][d];
            out[((size_t)b * DD + d) * NN + coln] = zv + (evv - zv);
        }
    }
}

// ---------------------------------------------------------------------------
extern "C" void kernel_launch(void* const* d_in, const int* in_sizes, int n_in,
                              void* d_out, int out_size, void* d_ws, size_t ws_size,
                              hipStream_t stream) {
    (void)in_sizes; (void)n_in; (void)out_size; (void)ws_size;
    const float* ze  = (const float*)d_in[0];   // (B, D, N) f32
    const float* emb = (const float*)d_in[1];   // (K, D)    f32
    float*       out = (float*)d_out;           // (B, D, N) f32

    char* ws = (char*)d_ws;
    short* epk = (short*)ws;                          // 256 KB packed -2*emb
    float* e2  = (float*)(ws + (size_t)KK * DD * 2);  // 4 KB (+CADD folded)

    emb_sq_kernel<<<KK / 256, 256, 0, stream>>>(emb, e2);
    emb_pack_kernel<<<(KK * DD / 8) / 256, 256, 0, stream>>>(emb, epk);
    vq_mfma<<<(BB * NN) / 32, 256, 0, stream>>>(ze, emb, epk, e2, out);
}

// Round 19
// 45.290 us; speedup vs baseline: 1.4924x; 1.0832x over previous
//
#include <hip/hip_runtime.h>
#include <hip/hip_bf16.h>
#include <math.h>

#define BB 16
#define DD 128
#define NN 4096
#define KK 1024
// Positivity shift folded into e2': m = e2 + CADD - 2<z,e> = d^2 + (CADD - z^2).
// z^2 ~ chi2(128): max over 65k cols ~ 205 << 320 -> m > 0 always. Key quant
// at m<=~740 is <=0.125; TAU covers flip-window + quantization.
#define CADD 320.0f
#define TAU 0.45f

typedef __attribute__((ext_vector_type(8))) short short8;
typedef __attribute__((ext_vector_type(4))) float f32x4;

static __device__ __forceinline__ unsigned short f32_bf16_rne(float f) {
    unsigned u = __float_as_uint(f);
    u += 0x7FFF + ((u >> 16) & 1);
    return (unsigned short)(u >> 16);
}
static __device__ __forceinline__ unsigned umin32(unsigned a, unsigned b) { return a < b ? a : b; }
static __device__ __forceinline__ unsigned umax32(unsigned a, unsigned b) { return a > b ? a : b; }
static __device__ __forceinline__ unsigned umed3(unsigned a, unsigned b, unsigned c) {
    unsigned d;
    asm("v_med3_u32 %0, %1, %2, %3" : "=v"(d) : "v"(a), "v"(b), "v"(c));
    return d;
}

// ---------------------------------------------------------------------------
// e2'[k] = ||emb[k]||^2 + CADD  (f32)
// ---------------------------------------------------------------------------
__global__ void emb_sq_kernel(const float* __restrict__ emb,
                              float* __restrict__ e2) {
    int k = blockIdx.x * 256 + threadIdx.x;
    if (k >= KK) return;
    const float4* row = reinterpret_cast<const float4*>(emb + (size_t)k * DD);
    float a0 = 0.f, a1 = 0.f, a2 = 0.f, a3 = 0.f;
#pragma unroll
    for (int i = 0; i < DD / 16; ++i) {
        float4 v0 = row[i * 4 + 0];
        float4 v1 = row[i * 4 + 1];
        float4 v2 = row[i * 4 + 2];
        float4 v3 = row[i * 4 + 3];
        a0 += v0.x * v0.x + v0.y * v0.y + v0.z * v0.z + v0.w * v0.w;
        a1 += v1.x * v1.x + v1.y * v1.y + v1.z * v1.z + v1.w * v1.w;
        a2 += v2.x * v2.x + v2.y * v2.y + v2.z * v2.z + v2.w * v2.w;
        a3 += v3.x * v3.x + v3.y * v3.y + v3.z * v3.z + v3.w * v3.w;
    }
    e2[k] = (a0 + a1) + (a2 + a3) + CADD;
}

// ---------------------------------------------------------------------------
// Pack (-2 * emb) as SINGLE bf16 in MFMA A-fragment order (256 KB).
// Fragment (t, s, lane): k = t*16 + (lane&15), d = s*32 + (lane>>4)*8 + j.
// ---------------------------------------------------------------------------
__global__ void emb_pack_kernel(const float* __restrict__ emb,
                                short* __restrict__ epk) {
    int g = blockIdx.x * 256 + threadIdx.x;     // 16384 fragment-slots
    int lane = g & 63;
    int s    = (g >> 6) & 3;
    int t    = g >> 8;
    int k = t * 16 + (lane & 15);
    int d = s * 32 + ((lane >> 4) & 3) * 8;
    const float* src = emb + (size_t)k * DD + d;
    short8 h;
#pragma unroll
    for (int j = 0; j < 8; ++j) h[j] = (short)f32_bf16_rne(-2.0f * src[j]);
    *reinterpret_cast<short8*>(epk + (size_t)g * 8) = h;
}

// CE on packed u32 keys: a <- min, b <- max (2 VALU, no vcc)
#define CEU(a, b) { unsigned lo_ = umin32(a, b), hi_ = umax32(a, b); (a) = lo_; (b) = hi_; }
// merge two ascending-4 key lists; lowest 4 end sorted in A1..A4
#define MRG9(A1, A2, A3, A4, B1, B2, B3, B4) \
    CEU(A1, B1) CEU(A2, B2) CEU(A3, B3) CEU(A4, B4) \
    CEU(A3, B1) CEU(A4, B2) \
    CEU(A2, A3) \
    CEU(A4, B1) \
    CEU(A3, A4)

// ---------------------------------------------------------------------------
// Round-19 (arithmetic-intensity round): wave = 64 cols (4 cgs) x 256 k;
// block = 64 cols, 4 waves split K quarters; grid 1024 (4 blocks/CU,
// 16 waves/CU). Per tile: 16 MFMAs per 5 loads -- 2x the compute per
// stream-byte of every 44-57us variant (r10-r18), and block-count halves
// the epk L2 traffic to ~256 MB. Register audit: zf 64 + acc 16 + keys 8 +
// misc ~20 = ~108 < 128 (the (256,4) budget) -- no explicit prefetch regs
// (compiler sinks them anyway, r16/r18 evidence). Key/trigger/refine/
// epilogue semantics as r12/r18 (absmax 0 x8), widened to 4 cgs.
// ---------------------------------------------------------------------------
__global__ __launch_bounds__(256, 4)
void vq_mfma(const float* __restrict__ ze, const float* __restrict__ emb,
             const short* __restrict__ epk, const float* __restrict__ e2,
             float* __restrict__ out) {
    // union: z-stage frags (16 KB) -> ew[64][129] (33 KB) after main loop
    __shared__ __align__(16) char ubuf[(DD + 1) * 64 * 4];   // 33024 B
    __shared__ unsigned kbuf[4][64][4];                      // 4 KB
    __shared__ int winner_s[64];
    __shared__ int rlist[64];
    __shared__ int rcnt;

    short* zstage = reinterpret_cast<short*>(ubuf);          // 8192 shorts

    const int tid  = threadIdx.x;
    const int lane = tid & 63;
    const int wave = tid >> 6;
    const int b    = blockIdx.x >> 6;             // 64 blocks per batch entry
    const int n0b  = (blockIdx.x & 63) * 64;      // block's 64-col base
    const float* zb = ze + (size_t)b * DD * NN;

    const int nq = lane & 15;
    const int dq = (lane >> 4) & 3;

    // ---- cooperative z staging: thread stages 4 frag slots (cg 0..3) ----
    // slot (cg, s=wave, lane): col = cg*16 + (lane&15), d = s*32+(lane>>4)*8+j
#pragma unroll
    for (int cg = 0; cg < 4; ++cg) {
        const int col = n0b + cg * 16 + nq;
        const int d0  = wave * 32 + dq * 8;
        const float* zp = zb + (size_t)d0 * NN + col;
        short8 h;
#pragma unroll
        for (int j = 0; j < 8; ++j) h[j] = (short)f32_bf16_rne(zp[(size_t)j * NN]);
        *reinterpret_cast<short8*>(zstage + (cg * 256 + wave * 64 + lane) * 8) = h;
    }
    __syncthreads();

    // ---- read zf frags from LDS (ds_read_b128, conflict-free) ----
    short8 zf[4][4];
#pragma unroll
    for (int cg = 0; cg < 4; ++cg)
#pragma unroll
        for (int s = 0; s < 4; ++s)
            zf[cg][s] = *reinterpret_cast<const short8*>(
                zstage + ((cg * 4 + s) * 64 + lane) * 8);
    __syncthreads();               // zstage dead; ubuf reusable as ew later

    // per-cg top-2 packed keys (ascending)
    unsigned K1[4], K2[4];
#pragma unroll
    for (int cg = 0; cg < 4; ++cg) { K1[cg] = K2[cg] = 0xFFFFFFFFu; }

    const int t0 = wave * 16;                     // this wave's 16 k-tiles
    const short* ep  = epk + (size_t)(t0 * 4) * 512 + (size_t)lane * 8;
    const float* e2p = e2 + t0 * 16 + dq * 4;
    unsigned kb = (unsigned)(t0 * 16 + dq * 4);

#pragma unroll 2
    for (int tt = 0; tt < 16; ++tt) {
        const short8 a0 = *reinterpret_cast<const short8*>(ep);
        const short8 a1 = *reinterpret_cast<const short8*>(ep + 512);
        const short8 a2 = *reinterpret_cast<const short8*>(ep + 1024);
        const short8 a3 = *reinterpret_cast<const short8*>(ep + 1536);
        const float4 ev = *reinterpret_cast<const float4*>(e2p);

        // acc init = e2' copy (CADD pre-folded)
        f32x4 acc0 = {ev.x, ev.y, ev.z, ev.w};
        f32x4 acc1 = acc0, acc2 = acc0, acc3 = acc0;
#define STEP(AF, S) \
        acc0 = __builtin_amdgcn_mfma_f32_16x16x32_bf16(AF, zf[0][S], acc0, 0, 0, 0); \
        acc1 = __builtin_amdgcn_mfma_f32_16x16x32_bf16(AF, zf[1][S], acc1, 0, 0, 0); \
        acc2 = __builtin_amdgcn_mfma_f32_16x16x32_bf16(AF, zf[2][S], acc2, 0, 0, 0); \
        acc3 = __builtin_amdgcn_mfma_f32_16x16x32_bf16(AF, zf[3][S], acc3, 0, 0, 0);
        STEP(a0, 0) STEP(a1, 1) STEP(a2, 2) STEP(a3, 3)
#undef STEP

#pragma unroll
        for (int cg = 0; cg < 4; ++cg) {
            const f32x4 a = (cg == 0) ? acc0 : (cg == 1) ? acc1
                          : (cg == 2) ? acc2 : acc3;       // cg is unroll-const
#pragma unroll
            for (int r = 0; r < 4; ++r) {
                const unsigned x = (__float_as_uint(a[r]) & 0xFFFFFC00u) | (kb + r);
                K2[cg] = umed3(K1[cg], K2[cg], x);         // new 2nd-best
                K1[cg] = umin32(K1[cg], x);                // new best
            }
        }
        kb += 16; ep += 2048; e2p += 16;
    }

    // ---- dq merge: 4 sorted-2 lists -> sorted top-4 of the 8 candidates ----
    unsigned T1[4], T2[4], T3[4], T4[4];
#pragma unroll
    for (int cg = 0; cg < 4; ++cg) {
        unsigned A1 = K1[cg], A2 = K2[cg];
        unsigned B1 = __shfl_xor(A1, 16);
        unsigned B2 = __shfl_xor(A2, 16);
        CEU(A1, B1) CEU(A2, B2) CEU(A2, B1)      // sorted4: A1,A2,B1,B2
        unsigned C1 = __shfl_xor(A1, 32);
        unsigned C2 = __shfl_xor(A2, 32);
        unsigned C3 = __shfl_xor(B1, 32);
        unsigned C4 = __shfl_xor(B2, 32);
        MRG9(A1, A2, B1, B2, C1, C2, C3, C4)
        T1[cg] = A1; T2[cg] = A2; T3[cg] = B1; T4[cg] = B2;
    }

    // lane c (0..63): column n0b + c has its list in cg = c>>4 (nested-ternary
    // select: no dynamic register indexing, rule-20 safe)
    {
        const int cgid = lane >> 4;
#define SEL4(T) ((cgid & 2) ? ((cgid & 1) ? T[3] : T[2]) : ((cgid & 1) ? T[1] : T[0]))
        kbuf[wave][lane][0] = SEL4(T1);
        kbuf[wave][lane][1] = SEL4(T2);
        kbuf[wave][lane][2] = SEL4(T3);
        kbuf[wave][lane][3] = SEL4(T4);
#undef SEL4
    }
    __syncthreads();

    // ---- wave 0: merge the 4 k-quarters per column, build refine list ----
    if (wave == 0) {
        const int c = lane;                        // 64 cols, 64 lanes
        unsigned A1 = kbuf[0][c][0], A2 = kbuf[0][c][1];
        unsigned A3 = kbuf[0][c][2], A4 = kbuf[0][c][3];
#pragma unroll
        for (int q = 1; q < 4; ++q) {
            unsigned B1 = kbuf[q][c][0], B2 = kbuf[q][c][1];
            unsigned B3 = kbuf[q][c][2], B4 = kbuf[q][c][3];
            MRG9(A1, A2, A3, A4, B1, B2, B3, B4)
        }
        const float M1 = __uint_as_float(A1 & 0xFFFFFC00u);
        const float M2 = __uint_as_float(A2 & 0xFFFFFC00u);
        const bool trig = (M2 - M1) < TAU;
        winner_s[c] = (int)(A1 & 0x3FFu);
        kbuf[0][c][0] = A1; kbuf[0][c][1] = A2;   // refine candidates
        kbuf[0][c][2] = A3; kbuf[0][c][3] = A4;
        const unsigned long long mask = __ballot(trig);
        if (trig) {
            const int idx = __popcll(mask & ((1ull << lane) - 1ull));
            rlist[idx] = c;
        }
        if (lane == 0) rcnt = (int)__popcll(mask);
    }
    __syncthreads();

    // ---- cooperative exact f64 refine (~15% of columns) ----
    {
        const int rc = rcnt;
        for (int j = wave; j < rc; j += 4) {
            const int c = rlist[j];
            const int coln = n0b + c;
            const int I0 = (int)(kbuf[0][c][0] & 0x3FFu);
            const int I1 = (int)(kbuf[0][c][1] & 0x3FFu);
            const int I2 = (int)(kbuf[0][c][2] & 0x3FFu);
            const int I3 = (int)(kbuf[0][c][3] & 0x3FFu);
            double s0 = 0.0, s1 = 0.0, s2 = 0.0, s3 = 0.0;
#pragma unroll
            for (int h = 0; h < 2; ++h) {
                const int d = h * 64 + lane;
                const double zv = (double)zb[(size_t)d * NN + coln];
                double q;
                q = zv - (double)emb[(size_t)I0 * DD + d]; s0 += q * q;
                q = zv - (double)emb[(size_t)I1 * DD + d]; s1 += q * q;
                q = zv - (double)emb[(size_t)I2 * DD + d]; s2 += q * q;
                q = zv - (double)emb[(size_t)I3 * DD + d]; s3 += q * q;
            }
#pragma unroll
            for (int off = 1; off < 64; off <<= 1) {
                s0 += __shfl_xor(s0, off);
                s1 += __shfl_xor(s1, off);
                s2 += __shfl_xor(s2, off);
                s3 += __shfl_xor(s3, off);
            }
            int best = I0; double db = s0;
            if (s1 < db || (s1 == db && I1 < best)) { db = s1; best = I1; }
            if (s2 < db || (s2 == db && I2 < best)) { db = s2; best = I2; }
            if (s3 < db || (s3 == db && I3 < best)) { db = s3; best = I3; }
            if (lane == 0) winner_s[c] = best;
        }
    }
    __syncthreads();

    // ---- epilogue: stage 64 winner rows in LDS (ubuf reuse), coalesced out
    float (*ew)[DD + 1] = reinterpret_cast<float(*)[DD + 1]>(ubuf);
#pragma unroll 4
    for (int rr = 0; rr < 16; ++rr) {
        const int r = wave * 16 + rr;
        const int idx = winner_s[r];                  // wave-uniform per iter
        ew[r][lane]      = emb[(size_t)idx * DD + lane];
        ew[r][lane + 64] = emb[(size_t)idx * DD + lane + 64];
    }
    __syncthreads();

    // lane = col (64 cols); wave covers d = wave*32 .. +32
    {
        const int coln = n0b + lane;
#pragma unroll 4
        for (int dd = 0; dd < 32; ++dd) {
            const int d = wave * 32 + dd;
            const float zv = zb[(size_t)d * NN + coln];
            const float evv = ew[lane][d];
            out[((size_t)b * DD + d) * NN + coln] = zv + (evv - zv);
        }
    }
}

// ---------------------------------------------------------------------------
extern "C" void kernel_launch(void* const* d_in, const int* in_sizes, int n_in,
                              void* d_out, int out_size, void* d_ws, size_t ws_size,
                              hipStream_t stream) {
    (void)in_sizes; (void)n_in; (void)out_size; (void)ws_size;
    const float* ze  = (const float*)d_in[0];   // (B, D, N) f32
    const float* emb = (const float*)d_in[1];   // (K, D)    f32
    float*       out = (float*)d_out;           // (B, D, N) f32

    char* ws = (char*)d_ws;
    short* epk = (short*)ws;                          // 256 KB packed -2*emb
    float* e2  = (float*)(ws + (size_t)KK * DD * 2);  // 4 KB (+CADD folded)

    emb_sq_kernel<<<KK / 256, 256, 0, stream>>>(emb, e2);
    emb_pack_kernel<<<(KK * DD / 8) / 256, 256, 0, stream>>>(emb, epk);
    vq_mfma<<<(BB * NN) / 64, 256, 0, stream>>>(ze, emb, epk, e2, out);
}